// Round 4
// baseline (163.082 us; speedup 1.0000x reference)
//
#include <hip/hip_runtime.h>
#include <math.h>

#define HH 512
#define WW 512
#define PHH 16
#define PWW 16
#define QQ 3
#define NHH 32
#define NWW 32
#define PP 1024
#define BB 64

// Twiddles: TW[j] = exp(-2*pi*i*j/16), j = 0..7
__device__ __constant__ float TWC[8] = {
    1.0f,  0.92387953251f,  0.70710678119f,  0.38268343236f,
    0.0f, -0.38268343236f, -0.70710678119f, -0.92387953251f};
__device__ __constant__ float TWS[8] = {
    0.0f, -0.38268343236f, -0.70710678119f, -0.92387953251f,
   -1.0f, -0.92387953251f, -0.70710678119f, -0.38268343236f};

// Fully-unrolled in-register 16-point complex FFT (radix-2 DIT).
// SGN=+1: forward (exp(-i)); SGN=-1: unscaled inverse (exp(+i)).
template <int SGN>
__device__ __forceinline__ void fft16(float* re, float* im) {
#define SWAP_(a, b)                              \
  { float t = re[a]; re[a] = re[b]; re[b] = t;   \
    t = im[a]; im[a] = im[b]; im[b] = t; }
  SWAP_(1, 8) SWAP_(2, 4) SWAP_(3, 12) SWAP_(5, 10) SWAP_(7, 14) SWAP_(11, 13)
#undef SWAP_
#pragma unroll
  for (int len = 2; len <= 16; len <<= 1) {
    const int half = len >> 1;
    const int tstep = 16 / len;
#pragma unroll
    for (int i = 0; i < 16; i += len) {
#pragma unroll
      for (int j = 0; j < half; ++j) {
        const float wr = TWC[j * tstep];
        const float wi = (SGN > 0) ? TWS[j * tstep] : -TWS[j * tstep];
        const int a = i + j;
        const int c = i + j + half;
        const float tr = re[c] * wr - im[c] * wi;
        const float ti = re[c] * wi + im[c] * wr;
        re[c] = re[a] - tr;
        im[c] = im[a] - ti;
        re[a] = re[a] + tr;
        im[a] = im[a] + ti;
      }
    }
  }
}

// Block: 256 threads = 16 groups x 16 lanes. Block handles one patch p and
// 32 batch indices: group g packs batches (b0+2g, b0+2g+1) as one complex
// image z = x_b1 + i*x_b2. S is real and 2D-even (S[-k,-l]=S[k,l], exact
// even in FP since g1/g2 mirror), so ifft2(fft2(x)*S) is exactly real for
// real x; Re -> y_b1, Im -> y_b2.
//
// LDS: ONE 17 KB tile buffer shared by re and im transposes sequentially
// (7 barriers). 18432 B/block -> 8 blocks/CU residency, vs 4 with separate
// re/im buffers. DS op count identical.
__global__ __launch_bounds__(256) void psm_kernel(
    const float* __restrict__ x, const float* __restrict__ logits,
    const float* __restrict__ mu, const float* __restrict__ sigma,
    const float* __restrict__ bias, float* __restrict__ out) {
  __shared__ float S_lds[256];
  __shared__ float tile[16 * 272];  // 16 groups, 16x16 tile, row stride 17

  const int tid = threadIdx.x;
  const int p = blockIdx.x >> 1;
  const int b0 = (blockIdx.x & 1) << 5;  // 0 or 32
  const int g = tid >> 4;
  const int r = tid & 15;
  const int b1 = b0 + 2 * g;
  const int nh = p >> 5;
  const int nw = p & 31;

  // ---- issue the x loads early so they overlap the S computation ----
  const size_t rowbase = (size_t)(nh * PHH + r) * WW + (size_t)(nw * PWW);
  const float* x1 = x + (size_t)b1 * (HH * WW) + rowbase;
  const float* x2 = x1 + (size_t)(HH * WW);
  const float4 a0 = ((const float4*)x1)[0];
  const float4 a1 = ((const float4*)x1)[1];
  const float4 a2 = ((const float4*)x1)[2];
  const float4 a3 = ((const float4*)x1)[3];
  const float4 c0 = ((const float4*)x2)[0];
  const float4 c1 = ((const float4*)x2)[1];
  const float4 c2 = ((const float4*)x2)[2];
  const float4 c3 = ((const float4*)x2)[3];

  // ---- spectral filter S for this patch into LDS (one bin/thread) ----
  {
    const int fy_i = tid >> 4;
    const int fx_i = tid & 15;
    const float fy = (float)(fy_i < 8 ? fy_i : fy_i - 16) * (1.0f / 16.0f);
    const float fx = (float)(fx_i < 8 ? fx_i : fx_i - 16) * (1.0f / 16.0f);
    const float l0 = logits[p * QQ + 0];
    const float l1 = logits[p * QQ + 1];
    const float l2 = logits[p * QQ + 2];
    const float lm = fmaxf(l0, fmaxf(l1, l2));
    const float e0 = __expf(l0 - lm);
    const float e1 = __expf(l1 - lm);
    const float e2 = __expf(l2 - lm);
    const float inv = 1.0f / (e0 + e1 + e2);
    const float wq[3] = {e0 * inv, e1 * inv, e2 * inv};
    float s = 0.0f;
#pragma unroll
    for (int q = 0; q < QQ; ++q) {
      const float muy = mu[(p * QQ + q) * 2 + 0];
      const float mux = mu[(p * QQ + q) * 2 + 1];
      const float isy = 1.0f / sigma[(p * QQ + q) * 2 + 0];
      const float isx = 1.0f / sigma[(p * QQ + q) * 2 + 1];
      const float dy1 = (fy - muy) * isy;
      const float dx1 = (fx - mux) * isx;
      const float dy2 = (fy + muy) * isy;
      const float dx2 = (fx + mux) * isx;
      const float g1 = __expf(-0.5f * (dy1 * dy1 + dx1 * dx1));
      const float g2 = __expf(-0.5f * (dy2 * dy2 + dx2 * dx2));
      s += wq[q] * (g1 + g2);
    }
    // fold jitter and the ifft2 1/256 normalization into S
    S_lds[tid] = (s + 1e-6f) * (1.0f / 256.0f);
  }
  // no barrier here: barrier B1 below also publishes S_lds (first S read
  // happens after B3).

  // ---- forward row FFT on packed complex rows z = x_b1 + i*x_b2 ----
  float re[16], im[16];
  re[0] = a0.x;  re[1] = a0.y;  re[2] = a0.z;  re[3] = a0.w;
  re[4] = a1.x;  re[5] = a1.y;  re[6] = a1.z;  re[7] = a1.w;
  re[8] = a2.x;  re[9] = a2.y;  re[10] = a2.z; re[11] = a2.w;
  re[12] = a3.x; re[13] = a3.y; re[14] = a3.z; re[15] = a3.w;
  im[0] = c0.x;  im[1] = c0.y;  im[2] = c0.z;  im[3] = c0.w;
  im[4] = c1.x;  im[5] = c1.y;  im[6] = c1.z;  im[7] = c1.w;
  im[8] = c2.x;  im[9] = c2.y;  im[10] = c2.z; im[11] = c2.w;
  im[12] = c3.x; im[13] = c3.y; im[14] = c3.z; im[15] = c3.w;
  fft16<1>(re, im);

  // ---- transpose #1 via shared single buffer: re pass, then im pass ----
  float* mt = &tile[g * 272];
#pragma unroll
  for (int c = 0; c < 16; ++c) mt[r * 17 + c] = re[c];
  __syncthreads();  // B1: re tiles + S_lds published
#pragma unroll
  for (int k = 0; k < 16; ++k) re[k] = mt[k * 17 + r];
  __syncthreads();  // B2: WAR, everyone done reading re tiles
#pragma unroll
  for (int c = 0; c < 16; ++c) mt[r * 17 + c] = im[c];
  __syncthreads();  // B3: im tiles published
#pragma unroll
  for (int k = 0; k < 16; ++k) im[k] = mt[k * 17 + r];

  // ---- column FFT, multiply by S, inverse column FFT ----
  fft16<1>(re, im);
#pragma unroll
  for (int k = 0; k < 16; ++k) {
    const float s = S_lds[k * 16 + r];
    re[k] *= s;
    im[k] *= s;
  }
  fft16<-1>(re, im);

  // ---- transpose #2 (column write, row read): re pass, then im pass ----
  __syncthreads();  // B4: WAR, everyone done reading im tiles
#pragma unroll
  for (int k = 0; k < 16; ++k) mt[k * 17 + r] = re[k];
  __syncthreads();  // B5: re tiles published
#pragma unroll
  for (int c = 0; c < 16; ++c) re[c] = mt[r * 17 + c];
  __syncthreads();  // B6: WAR
#pragma unroll
  for (int k = 0; k < 16; ++k) mt[k * 17 + r] = im[k];
  __syncthreads();  // B7: im tiles published
#pragma unroll
  for (int c = 0; c < 16; ++c) im[c] = mt[r * 17 + c];

  // ---- inverse row FFT: re -> y_b1, im -> y_b2 ----
  fft16<-1>(re, im);

  // ---- bias (shared by both batches) + DE-INTERLEAVED vector stores ----
  // Each lane completes its full 64B line for o1 before touching o2, so
  // the write-combine path sees whole lines (R3's interleaved stores gave
  // WRITE_SIZE 2.2x ideal).
  const float* brow = bias + (size_t)p * 256 + (size_t)r * 16;
  const float4 bv0 = ((const float4*)brow)[0];
  const float4 bv1 = ((const float4*)brow)[1];
  const float4 bv2 = ((const float4*)brow)[2];
  const float4 bv3 = ((const float4*)brow)[3];
  float* o1 = out + (size_t)b1 * (HH * WW) + rowbase;
  float* o2 = o1 + (size_t)(HH * WW);

  float4 u0, u1, u2, u3;
  u0.x = re[0] + bv0.x;   u0.y = re[1] + bv0.y;
  u0.z = re[2] + bv0.z;   u0.w = re[3] + bv0.w;
  u1.x = re[4] + bv1.x;   u1.y = re[5] + bv1.y;
  u1.z = re[6] + bv1.z;   u1.w = re[7] + bv1.w;
  u2.x = re[8] + bv2.x;   u2.y = re[9] + bv2.y;
  u2.z = re[10] + bv2.z;  u2.w = re[11] + bv2.w;
  u3.x = re[12] + bv3.x;  u3.y = re[13] + bv3.y;
  u3.z = re[14] + bv3.z;  u3.w = re[15] + bv3.w;
  ((float4*)o1)[0] = u0;
  ((float4*)o1)[1] = u1;
  ((float4*)o1)[2] = u2;
  ((float4*)o1)[3] = u3;

  float4 v0, v1, v2, v3;
  v0.x = im[0] + bv0.x;   v0.y = im[1] + bv0.y;
  v0.z = im[2] + bv0.z;   v0.w = im[3] + bv0.w;
  v1.x = im[4] + bv1.x;   v1.y = im[5] + bv1.y;
  v1.z = im[6] + bv1.z;   v1.w = im[7] + bv1.w;
  v2.x = im[8] + bv2.x;   v2.y = im[9] + bv2.y;
  v2.z = im[10] + bv2.z;  v2.w = im[11] + bv2.w;
  v3.x = im[12] + bv3.x;  v3.y = im[13] + bv3.y;
  v3.z = im[14] + bv3.z;  v3.w = im[15] + bv3.w;
  ((float4*)o2)[0] = v0;
  ((float4*)o2)[1] = v1;
  ((float4*)o2)[2] = v2;
  ((float4*)o2)[3] = v3;
}

extern "C" void kernel_launch(void* const* d_in, const int* in_sizes, int n_in,
                              void* d_out, int out_size, void* d_ws,
                              size_t ws_size, hipStream_t stream) {
  (void)in_sizes;
  (void)n_in;
  (void)out_size;
  (void)d_ws;
  (void)ws_size;
  const float* x = (const float*)d_in[0];
  const float* logits = (const float*)d_in[1];
  const float* mu = (const float*)d_in[2];
  const float* sigma = (const float*)d_in[3];
  const float* bias = (const float*)d_in[4];
  float* out = (float*)d_out;

  // 1024 patches x 2 batch-chunks of 32 (16 groups x 2 packed batches)
  psm_kernel<<<dim3(PP * 2), dim3(256), 0, stream>>>(x, logits, mu, sigma,
                                                     bias, out);
}

// Round 5
// 157.705 us; speedup vs baseline: 1.0341x; 1.0341x over previous
//
#include <hip/hip_runtime.h>
#include <math.h>

#define HH 512
#define WW 512
#define PHH 16
#define PWW 16
#define QQ 3
#define NHH 32
#define NWW 32
#define PP 1024
#define BB 64

// Twiddles: TW[j] = exp(-2*pi*i*j/16), j = 0..7
__device__ __constant__ float TWC[8] = {
    1.0f,  0.92387953251f,  0.70710678119f,  0.38268343236f,
    0.0f, -0.38268343236f, -0.70710678119f, -0.92387953251f};
__device__ __constant__ float TWS[8] = {
    0.0f, -0.38268343236f, -0.70710678119f, -0.92387953251f,
   -1.0f, -0.92387953251f, -0.70710678119f, -0.38268343236f};

// Wave-local LDS ordering: all lanes of a wave are lockstep; after this
// wait every ds_write issued by this wave is committed, so a subsequent
// ds_read by any lane of the SAME wave sees it. No block rendezvous.
#define WAVE_LDS_FENCE() asm volatile("s_waitcnt lgkmcnt(0)" ::: "memory")

// Fully-unrolled in-register 16-point complex FFT (radix-2 DIT).
// SGN=+1: forward (exp(-i)); SGN=-1: unscaled inverse (exp(+i)).
template <int SGN>
__device__ __forceinline__ void fft16(float* re, float* im) {
#define SWAP_(a, b)                              \
  { float t = re[a]; re[a] = re[b]; re[b] = t;   \
    t = im[a]; im[a] = im[b]; im[b] = t; }
  SWAP_(1, 8) SWAP_(2, 4) SWAP_(3, 12) SWAP_(5, 10) SWAP_(7, 14) SWAP_(11, 13)
#undef SWAP_
#pragma unroll
  for (int len = 2; len <= 16; len <<= 1) {
    const int half = len >> 1;
    const int tstep = 16 / len;
#pragma unroll
    for (int i = 0; i < 16; i += len) {
#pragma unroll
      for (int j = 0; j < half; ++j) {
        const float wr = TWC[j * tstep];
        const float wi = (SGN > 0) ? TWS[j * tstep] : -TWS[j * tstep];
        const int a = i + j;
        const int c = i + j + half;
        const float tr = re[c] * wr - im[c] * wi;
        const float ti = re[c] * wi + im[c] * wr;
        re[c] = re[a] - tr;
        im[c] = im[a] - ti;
        re[a] = re[a] + tr;
        im[a] = im[a] + ti;
      }
    }
  }
}

// Block: 256 threads = 16 groups x 16 lanes; each group lives entirely in
// one wave64 (groups 4w..4w+3 -> wave w), so the per-group transpose tiles
// need NO block-wide barriers — only wave-local lgkmcnt fences.
// Group g packs batches (b0+2g, b0+2g+1) as z = x_b1 + i*x_b2; S is real,
// 2D-even => result exactly real per image => Re -> y_b1, Im -> y_b2.
// Tile element (row k, col c) lives at float2 index k*17+c: both row
// access (fixed k, lanes vary c... lanes ARE rows here) and column access
// are conflict-free: dword banks 2*(17r+c) mod 32 and 2*(17k+r) mod 32 are
// distinct across the 16 lanes of a group (spacing 2 mod 32).
__global__ __launch_bounds__(256, 4) void psm_kernel(
    const float* __restrict__ x, const float* __restrict__ logits,
    const float* __restrict__ mu, const float* __restrict__ sigma,
    const float* __restrict__ bias, float* __restrict__ out) {
  __shared__ float S_lds[256];
  __shared__ float2 tile[16 * 272];  // 16 groups x (16 rows x stride 17)

  const int tid = threadIdx.x;
  const int p = blockIdx.x >> 1;
  const int b0 = (blockIdx.x & 1) << 5;  // 0 or 32
  const int g = tid >> 4;
  const int r = tid & 15;
  const int b1 = b0 + 2 * g;
  const int nh = p >> 5;
  const int nw = p & 31;

  // ---- issue the x loads early so they overlap the S computation ----
  const size_t rowbase = (size_t)(nh * PHH + r) * WW + (size_t)(nw * PWW);
  const float* x1 = x + (size_t)b1 * (HH * WW) + rowbase;
  const float* x2 = x1 + (size_t)(HH * WW);
  const float4 a0 = ((const float4*)x1)[0];
  const float4 a1 = ((const float4*)x1)[1];
  const float4 a2 = ((const float4*)x1)[2];
  const float4 a3 = ((const float4*)x1)[3];
  const float4 c0 = ((const float4*)x2)[0];
  const float4 c1 = ((const float4*)x2)[1];
  const float4 c2 = ((const float4*)x2)[2];
  const float4 c3 = ((const float4*)x2)[3];

  // ---- spectral filter S for this patch into LDS (one bin/thread) ----
  {
    const int fy_i = tid >> 4;
    const int fx_i = tid & 15;
    const float fy = (float)(fy_i < 8 ? fy_i : fy_i - 16) * (1.0f / 16.0f);
    const float fx = (float)(fx_i < 8 ? fx_i : fx_i - 16) * (1.0f / 16.0f);
    const float l0 = logits[p * QQ + 0];
    const float l1 = logits[p * QQ + 1];
    const float l2 = logits[p * QQ + 2];
    const float lm = fmaxf(l0, fmaxf(l1, l2));
    const float e0 = __expf(l0 - lm);
    const float e1 = __expf(l1 - lm);
    const float e2 = __expf(l2 - lm);
    const float inv = 1.0f / (e0 + e1 + e2);
    const float wq[3] = {e0 * inv, e1 * inv, e2 * inv};
    float s = 0.0f;
#pragma unroll
    for (int q = 0; q < QQ; ++q) {
      const float muy = mu[(p * QQ + q) * 2 + 0];
      const float mux = mu[(p * QQ + q) * 2 + 1];
      const float isy = 1.0f / sigma[(p * QQ + q) * 2 + 0];
      const float isx = 1.0f / sigma[(p * QQ + q) * 2 + 1];
      const float dy1 = (fy - muy) * isy;
      const float dx1 = (fx - mux) * isx;
      const float dy2 = (fy + muy) * isy;
      const float dx2 = (fx + mux) * isx;
      const float g1 = __expf(-0.5f * (dy1 * dy1 + dx1 * dx1));
      const float g2 = __expf(-0.5f * (dy2 * dy2 + dx2 * dx2));
      s += wq[q] * (g1 + g2);
    }
    // fold jitter and the ifft2 1/256 normalization into S
    S_lds[tid] = (s + 1e-6f) * (1.0f / 256.0f);
  }

  // ---- forward row FFT on packed complex rows z = x_b1 + i*x_b2 ----
  float re[16], im[16];
  re[0] = a0.x;  re[1] = a0.y;  re[2] = a0.z;  re[3] = a0.w;
  re[4] = a1.x;  re[5] = a1.y;  re[6] = a1.z;  re[7] = a1.w;
  re[8] = a2.x;  re[9] = a2.y;  re[10] = a2.z; re[11] = a2.w;
  re[12] = a3.x; re[13] = a3.y; re[14] = a3.z; re[15] = a3.w;
  im[0] = c0.x;  im[1] = c0.y;  im[2] = c0.z;  im[3] = c0.w;
  im[4] = c1.x;  im[5] = c1.y;  im[6] = c1.z;  im[7] = c1.w;
  im[8] = c2.x;  im[9] = c2.y;  im[10] = c2.z; im[11] = c2.w;
  im[12] = c3.x; im[13] = c3.y; im[14] = c3.z; im[15] = c3.w;
  fft16<1>(re, im);

  // ---- write rows (lane r = row r), float2-packed ----
  float2* mt = &tile[g * 272];
#pragma unroll
  for (int c = 0; c < 16; ++c) mt[r * 17 + c] = make_float2(re[c], im[c]);

  // The ONLY block-wide barrier: publishes S_lds (cross-wave) and the row
  // tiles (wave-local anyway).
  __syncthreads();

  // ---- read column r ----
#pragma unroll
  for (int k = 0; k < 16; ++k) {
    const float2 v = mt[k * 17 + r];
    re[k] = v.x;
    im[k] = v.y;
  }

  // ---- column FFT, multiply by S, inverse column FFT ----
  fft16<1>(re, im);
#pragma unroll
  for (int k = 0; k < 16; ++k) {
    const float s = S_lds[k * 16 + r];
    re[k] *= s;
    im[k] *= s;
  }
  fft16<-1>(re, im);

  // Reads above must have landed before we overwrite the tile (wave-local).
  WAVE_LDS_FENCE();

  // ---- write column r back ----
#pragma unroll
  for (int k = 0; k < 16; ++k) mt[k * 17 + r] = make_float2(re[k], im[k]);

  // Publish column writes to the other lanes of this wave.
  WAVE_LDS_FENCE();

  // ---- read row r back ----
#pragma unroll
  for (int c = 0; c < 16; ++c) {
    const float2 v = mt[r * 17 + c];
    re[c] = v.x;
    im[c] = v.y;
  }

  // ---- inverse row FFT: re -> y_b1, im -> y_b2 ----
  fft16<-1>(re, im);

  // ---- bias (shared by both batches) + de-interleaved vector stores ----
  const float* brow = bias + (size_t)p * 256 + (size_t)r * 16;
  const float4 bv0 = ((const float4*)brow)[0];
  const float4 bv1 = ((const float4*)brow)[1];
  const float4 bv2 = ((const float4*)brow)[2];
  const float4 bv3 = ((const float4*)brow)[3];
  float* o1 = out + (size_t)b1 * (HH * WW) + rowbase;
  float* o2 = o1 + (size_t)(HH * WW);

  float4 u0, u1, u2, u3;
  u0.x = re[0] + bv0.x;   u0.y = re[1] + bv0.y;
  u0.z = re[2] + bv0.z;   u0.w = re[3] + bv0.w;
  u1.x = re[4] + bv1.x;   u1.y = re[5] + bv1.y;
  u1.z = re[6] + bv1.z;   u1.w = re[7] + bv1.w;
  u2.x = re[8] + bv2.x;   u2.y = re[9] + bv2.y;
  u2.z = re[10] + bv2.z;  u2.w = re[11] + bv2.w;
  u3.x = re[12] + bv3.x;  u3.y = re[13] + bv3.y;
  u3.z = re[14] + bv3.z;  u3.w = re[15] + bv3.w;
  ((float4*)o1)[0] = u0;
  ((float4*)o1)[1] = u1;
  ((float4*)o1)[2] = u2;
  ((float4*)o1)[3] = u3;

  float4 v0, v1, v2, v3;
  v0.x = im[0] + bv0.x;   v0.y = im[1] + bv0.y;
  v0.z = im[2] + bv0.z;   v0.w = im[3] + bv0.w;
  v1.x = im[4] + bv1.x;   v1.y = im[5] + bv1.y;
  v1.z = im[6] + bv1.z;   v1.w = im[7] + bv1.w;
  v2.x = im[8] + bv2.x;   v2.y = im[9] + bv2.y;
  v2.z = im[10] + bv2.z;  v2.w = im[11] + bv2.w;
  v3.x = im[12] + bv3.x;  v3.y = im[13] + bv3.y;
  v3.z = im[14] + bv3.z;  v3.w = im[15] + bv3.w;
  ((float4*)o2)[0] = v0;
  ((float4*)o2)[1] = v1;
  ((float4*)o2)[2] = v2;
  ((float4*)o2)[3] = v3;
}

extern "C" void kernel_launch(void* const* d_in, const int* in_sizes, int n_in,
                              void* d_out, int out_size, void* d_ws,
                              size_t ws_size, hipStream_t stream) {
  (void)in_sizes;
  (void)n_in;
  (void)out_size;
  (void)d_ws;
  (void)ws_size;
  const float* x = (const float*)d_in[0];
  const float* logits = (const float*)d_in[1];
  const float* mu = (const float*)d_in[2];
  const float* sigma = (const float*)d_in[3];
  const float* bias = (const float*)d_in[4];
  float* out = (float*)d_out;

  // 1024 patches x 2 batch-chunks of 32 (16 groups x 2 packed batches)
  psm_kernel<<<dim3(PP * 2), dim3(256), 0, stream>>>(x, logits, mu, sigma,
                                                     bias, out);
}